// Round 15
// baseline (96.132 us; speedup 1.0000x reference)
//
#include <hip/hip_runtime.h>

#define B_  16
#define S_  512
#define H_  768
#define T_  9
#define HD_ 64
#define N1  (T_*HD_*2)   // 1152
#define M1  (B_*S_)      // 8192
#define NT1 (H_/32)      // 24 K-tiles

typedef __attribute__((ext_vector_type(8))) short bf16x8;
typedef __attribute__((ext_vector_type(4))) float f32x4;

#define GLB(p) ((const __attribute__((address_space(1))) void*)(p))
#define LDSP(p) ((__attribute__((address_space(3))) void*)(p))

__device__ inline unsigned short f2bf(float f){
  union { float f; unsigned u; } v; v.f = f;
  unsigned r = v.u + 0x7fffu + ((v.u >> 16) & 1u);   // RNE
  return (unsigned short)(r >> 16);
}

__device__ inline void nt_store4(float* p, float x, float y, float z, float wv){
  f32x4 t = {x, y, z, wv};
  __builtin_nontemporal_store(t, (f32x4*)p);
}

// --- prep: W [768,1152] fp32 -> Wt [1152,768] bf16 transpose | trig table ---
__global__ __launch_bounds__(256) void prep_wt(
    const float* __restrict__ W, short* __restrict__ Wt, float2* __restrict__ tab)
{
  __shared__ float tile[32][33];
  const int bx = blockIdx.x, tid = threadIdx.x;
  if(bx < 864){
    int n0 = (bx % 36)*32, k0 = (bx / 36)*32;
    int tx = tid & 31, ty = tid >> 5;
    #pragma unroll
    for(int r = 0; r < 32; r += 8)
      tile[ty + r][tx] = W[(size_t)(k0 + ty + r)*N1 + n0 + tx];
    __syncthreads();
    #pragma unroll
    for(int r = 0; r < 32; r += 8)
      Wt[(size_t)(n0 + ty + r)*H_ + k0 + tx] = (short)f2bf(tile[tx][ty + r]);
  } else {
    int i = (bx - 864)*256 + tid;
    int s = i >> 5, p = i & 31;
    float inv = powf(10000.f, -2.f*(float)p/64.f);
    float a = (float)s * inv;
    tab[i] = make_float2(cosf(a), sinf(a));
  }
}

// --- GEMM1: 128x128, BK=32, 3-buffer pipeline, fused fp32->bf16 A staging.
// vmcnt never drains below 6 mid-loop (B(k+2)+A(k+3) always in flight).
__global__ __launch_bounds__(256, 3) void gemm1_rope(
    const float* __restrict__ hs, const short* __restrict__ Wt,
    const float* __restrict__ bias, const float2* __restrict__ tab,
    short* __restrict__ Qr, short* __restrict__ Kr)
{
  __shared__ short As[3][4096];       // 3 x 8 KB (128 rows x 32 k)
  __shared__ short Bs[3][4096];       // 3 x 8 KB
  const int tid  = threadIdx.x;
  const int lane = tid & 63, w = tid >> 6;
  const int lr = lane & 15, h = lane >> 4;
  const int lk = h * 8;
  const int wm = (w >> 1) * 64, wn = (w & 1) * 64;
  const int m0 = blockIdx.x * 128;    // 64 m-tiles
  const int n0 = blockIdx.y * 128;    // 9 n-tiles (= entity type)

  const float* aS = hs + (size_t)(m0 + (tid >> 2)) * H_ + (tid & 3) * 8;
  const short* bS = Wt + (size_t)(n0 + (tid >> 2)) * H_ + (tid & 3) * 8;
  const int dOff = tid * 8;           // shorts; rows 64..127 at +2048

  float4 rA0, rA1, rA2, rA3;          // buffer A of A-regs
  float4 rB0, rB1, rB2, rB3;          // buffer B of A-regs

#define LOAD_A(RA0,RA1,RA2,RA3, k0) do{ \
    RA0 = *(const float4*)(aS + (k0));            RA1 = *(const float4*)(aS + (k0) + 4); \
    RA2 = *(const float4*)(aS + 64*H_ + (k0));    RA3 = *(const float4*)(aS + 64*H_ + (k0) + 4); \
  }while(0)

#define CVT_DSWRITE(buf, RA0,RA1,RA2,RA3) do{ \
    bf16x8 t0_, t1_; \
    t0_[0]=f2bf(RA0.x); t0_[1]=f2bf(RA0.y); t0_[2]=f2bf(RA0.z); t0_[3]=f2bf(RA0.w); \
    t0_[4]=f2bf(RA1.x); t0_[5]=f2bf(RA1.y); t0_[6]=f2bf(RA1.z); t0_[7]=f2bf(RA1.w); \
    t1_[0]=f2bf(RA2.x); t1_[1]=f2bf(RA2.y); t1_[2]=f2bf(RA2.z); t1_[3]=f2bf(RA2.w); \
    t1_[4]=f2bf(RA3.x); t1_[5]=f2bf(RA3.y); t1_[6]=f2bf(RA3.z); t1_[7]=f2bf(RA3.w); \
    *(bf16x8*)(&As[buf][dOff]) = t0_; \
    *(bf16x8*)(&As[buf][dOff + 2048]) = t1_; \
  }while(0)

#define STAGE_B(buf, k0) do{ \
    __builtin_amdgcn_global_load_lds(GLB(bS + (k0)),         LDSP(&Bs[buf][dOff]),        16, 0, 0); \
    __builtin_amdgcn_global_load_lds(GLB(bS + 64*H_ + (k0)), LDSP(&Bs[buf][dOff + 2048]), 16, 0, 0); \
  }while(0)

  f32x4 acc[4][4] = {};

  // prologue: A(0)->rA, cvt(0); B(0); A(1)->rB; B(1); A(2)->rA
  LOAD_A(rA0,rA1,rA2,rA3, 0);
  CVT_DSWRITE(0, rA0,rA1,rA2,rA3);
  STAGE_B(0, 0);
  LOAD_A(rB0,rB1,rB2,rB3, 32);
  STAGE_B(1, 64);
  LOAD_A(rA0,rA1,rA2,rA3, 64);
  asm volatile("s_waitcnt vmcnt(6) lgkmcnt(0)\n\ts_barrier" ::: "memory");

  #pragma unroll
  for(int k = 0; k < NT1; ++k){
    const int cb = k % 3;                    // compute buffer (static: full unroll)
    // tile k+1: regs -> LDS  (parity: tile t lives in ra[t&1])
    if(k + 1 < NT1){
      if((k + 1) & 1) CVT_DSWRITE((k+1)%3, rB0,rB1,rB2,rB3);
      else            CVT_DSWRITE((k+1)%3, rA0,rA1,rA2,rA3);
    }
    if(k + 2 < NT1) STAGE_B((k+2)%3, (k + 2) * 32);
    if(k + 3 < NT1){
      if((k + 3) & 1) { LOAD_A(rB0,rB1,rB2,rB3, (k + 3) * 32); }
      else            { LOAD_A(rA0,rA1,rA2,rA3, (k + 3) * 32); }
    }

    bf16x8 aF[4], bF[4];
    #pragma unroll
    for(int i = 0; i < 4; ++i) aF[i] = *(const bf16x8*)(&As[cb][(wm + i*16 + lr)*32 + lk]);
    #pragma unroll
    for(int j = 0; j < 4; ++j) bF[j] = *(const bf16x8*)(&Bs[cb][(wn + j*16 + lr)*32 + lk]);
    #pragma unroll
    for(int i = 0; i < 4; ++i)
      #pragma unroll
      for(int j = 0; j < 4; ++j)
        acc[i][j] = __builtin_amdgcn_mfma_f32_16x16x32_bf16(bF[j], aF[i], acc[i][j], 0, 0, 0);

    // end of iter: tile k+1 (B-stage + my ds_write) must be resident for all waves
    if(k + 2 < NT1)      asm volatile("s_waitcnt vmcnt(6) lgkmcnt(0)\n\ts_barrier" ::: "memory");
    else if(k + 1 < NT1) asm volatile("s_waitcnt vmcnt(0) lgkmcnt(0)\n\ts_barrier" ::: "memory");
  }

  // epilogue: bias + lane-local RoPE + packed 4B stores (regs = 4 consecutive n)
  const int t = blockIdx.y;
  #pragma unroll
  for(int i = 0; i < 4; ++i){
    int m  = m0 + wm + i*16 + lr;
    int bi = m >> 9, sp = m & 511;
    size_t rowoff = ((size_t)(bi*T_ + t)*S_ + sp)*HD_;
    #pragma unroll
    for(int j = 0; j < 4; ++j){
      int nq  = n0 + wn + j*16 + (h << 2);
      int hd0 = (nq >> 1) & 63;
      int p   = (nq >> 2) & 31;
      float4 bv = *(const float4*)(bias + nq);
      float2 cs = tab[sp*32 + p];
      float q0 = acc[i][j][0] + bv.x;
      float k0v= acc[i][j][1] + bv.y;
      float q1 = acc[i][j][2] + bv.z;
      float k1v= acc[i][j][3] + bv.w;
      float rq0 = q0*cs.x - q1*cs.y, rq1 = q1*cs.x + q0*cs.y;
      float rk0 = k0v*cs.x - k1v*cs.y, rk1 = k1v*cs.x + k0v*cs.y;
      unsigned uq = (unsigned)f2bf(rq0) | ((unsigned)f2bf(rq1) << 16);
      unsigned uk = (unsigned)f2bf(rk0) | ((unsigned)f2bf(rk1) << 16);
      *(unsigned*)(Qr + rowoff + hd0) = uq;
      *(unsigned*)(Kr + rowoff + hd0) = uk;
    }
  }
#undef LOAD_A
#undef CVT_DSWRITE
#undef STAGE_B
}

// --- biaffine, XCD-swizzled, triangle-classified, nontemporal stores ---
__global__ __launch_bounds__(256) void gemm2_mask(
    const short* __restrict__ Qr, const short* __restrict__ Kr,
    const int* __restrict__ am, float* __restrict__ out)
{
  const int lane = threadIdx.x & 63;
  const int w    = threadIdx.x >> 6;
  const int wg   = ((blockIdx.x & 7) * 288) + (blockIdx.x >> 3);
  const int bt   = wg >> 4;
  const int tile = wg & 15;
  const int mt   = tile >> 2, nt = tile & 3;
  const int b    = bt / T_;
  const int n0   = nt * 128 + (w & 1) * 64;
  const int m0   = mt * 128 + (w >> 1) * 64;
  const int lr   = lane & 15;
  const int lk   = (lane >> 4) * 8;
  const int* amb = am + b * S_;

  if(mt > nt){                         // strictly lower: constant under fp32 rounding
    #pragma unroll
    for(int i = 0; i < 4; ++i){
      int m = m0 + i*16 + lr;
      float amm = (float)amb[m];
      float* orow = out + ((size_t)bt*S_ + m)*S_;
      #pragma unroll
      for(int j = 0; j < 4; ++j){
        int nq = n0 + j*16 + ((lane >> 4) << 2);
        int4 a4 = *(const int4*)(amb + nq);
        nt_store4(orow + nq,
                  -(1.f - amm*(float)a4.x)*1e12f - 1e12f,
                  -(1.f - amm*(float)a4.y)*1e12f - 1e12f,
                  -(1.f - amm*(float)a4.z)*1e12f - 1e12f,
                  -(1.f - amm*(float)a4.w)*1e12f - 1e12f);
      }
    }
    return;
  }

  const short* Q = Qr + (size_t)bt * S_ * HD_;
  const short* K = Kr + (size_t)bt * S_ * HD_;
  f32x4 acc[4][4] = {};

  #pragma unroll
  for(int ks = 0; ks < HD_; ks += 32){
    bf16x8 aF[4], bF[4];
    #pragma unroll
    for(int i = 0; i < 4; ++i) aF[i] = *(const bf16x8*)(Q + (size_t)(m0 + i*16 + lr)*HD_ + ks + lk);
    #pragma unroll
    for(int j = 0; j < 4; ++j) bF[j] = *(const bf16x8*)(K + (size_t)(n0 + j*16 + lr)*HD_ + ks + lk);
    #pragma unroll
    for(int i = 0; i < 4; ++i)
      #pragma unroll
      for(int j = 0; j < 4; ++j)
        acc[i][j] = __builtin_amdgcn_mfma_f32_16x16x32_bf16(bF[j], aF[i], acc[i][j], 0, 0, 0);
  }

  const bool diag = (mt == nt);
  #pragma unroll
  for(int i = 0; i < 4; ++i){
    int m = m0 + i*16 + lr;
    float amm = (float)amb[m];
    float* orow = out + ((size_t)bt*S_ + m)*S_;
    #pragma unroll
    for(int j = 0; j < 4; ++j){
      int nq = n0 + j*16 + ((lane >> 4) << 2);
      int4 a4 = *(const int4*)(amb + nq);
      float rx = acc[i][j][0]*0.125f - (1.f - amm*(float)a4.x)*1e12f;
      float ry = acc[i][j][1]*0.125f - (1.f - amm*(float)a4.y)*1e12f;
      float rz = acc[i][j][2]*0.125f - (1.f - amm*(float)a4.z)*1e12f;
      float rw = acc[i][j][3]*0.125f - (1.f - amm*(float)a4.w)*1e12f;
      if(diag){
        if((nq+0) < m) rx -= 1e12f;
        if((nq+1) < m) ry -= 1e12f;
        if((nq+2) < m) rz -= 1e12f;
        if((nq+3) < m) rw -= 1e12f;
      }
      nt_store4(orow + nq, rx, ry, rz, rw);
    }
  }
}

extern "C" void kernel_launch(void* const* d_in, const int* in_sizes, int n_in,
                              void* d_out, int out_size, void* d_ws, size_t ws_size,
                              hipStream_t stream)
{
  const float* hs    = (const float*)d_in[0];
  const int*   amask = (const int*)  d_in[1];
  const float* W     = (const float*)d_in[2];
  const float* bias  = (const float*)d_in[3];
  float* out = (float*)d_out;

  char* ws = (char*)d_ws;
  short*  Wt  = (short*) (ws);                       // 1,769,472 B
  float2* tab = (float2*)(ws + 1769472);             //   131,072 B
  short*  Qr  = (short*) (ws + 1900544);             // 9,437,184 B
  short*  Kr  = (short*) (ws + 11337728);            // 9,437,184 B

  prep_wt   <<<928, 256, 0, stream>>>(W, Wt, tab);
  gemm1_rope<<<dim3(M1/128, N1/128), 256, 0, stream>>>(hs, Wt, bias, tab, Qr, Kr);
  gemm2_mask<<<2304, 256, 0, stream>>>(Qr, Kr, amask, out);
}

// Round 16
// 94.185 us; speedup vs baseline: 1.0207x; 1.0207x over previous
//
#include <hip/hip_runtime.h>

#define B_  16
#define S_  512
#define H_  768
#define T_  9
#define HD_ 64
#define N1  (T_*HD_*2)   // 1152
#define M1  (B_*S_)      // 8192
#define NT1 (H_/32)      // 24 K-tiles

typedef __attribute__((ext_vector_type(8))) short bf16x8;
typedef __attribute__((ext_vector_type(4))) float f32x4;

#define GLB(p) ((const __attribute__((address_space(1))) void*)(p))
#define LDSP(p) ((__attribute__((address_space(3))) void*)(p))

__device__ inline unsigned short f2bf(float f){
  union { float f; unsigned u; } v; v.f = f;
  unsigned r = v.u + 0x7fffu + ((v.u >> 16) & 1u);   // RNE
  return (unsigned short)(r >> 16);
}

__device__ inline void nt_store4(float* p, float x, float y, float z, float wv){
  f32x4 t = {x, y, z, wv};
  __builtin_nontemporal_store(t, (f32x4*)p);
}

// --- merged prep: hs->bf16 | W transpose->bf16 | trig table ---
__global__ __launch_bounds__(256) void prep_all(
    const float* __restrict__ hs, short* __restrict__ Abf,
    const float* __restrict__ W, short* __restrict__ Wt,
    float2* __restrict__ tab)
{
  __shared__ float tile[32][33];
  const int bx = blockIdx.x, tid = threadIdx.x;
  if(bx < 3072){
    int i = bx*2048 + tid*8;
    float4 a0 = *(const float4*)(hs + i);
    float4 a1 = *(const float4*)(hs + i + 4);
    bf16x8 r;
    r[0]=f2bf(a0.x); r[1]=f2bf(a0.y); r[2]=f2bf(a0.z); r[3]=f2bf(a0.w);
    r[4]=f2bf(a1.x); r[5]=f2bf(a1.y); r[6]=f2bf(a1.z); r[7]=f2bf(a1.w);
    *(bf16x8*)(Abf + i) = r;
  } else if(bx < 3936){
    int idx = bx - 3072;
    int n0 = (idx % 36)*32, k0 = (idx / 36)*32;
    int tx = tid & 31, ty = tid >> 5;
    #pragma unroll
    for(int r = 0; r < 32; r += 8)
      tile[ty + r][tx] = W[(size_t)(k0 + ty + r)*N1 + n0 + tx];
    __syncthreads();
    #pragma unroll
    for(int r = 0; r < 32; r += 8)
      Wt[(size_t)(n0 + ty + r)*H_ + k0 + tx] = (short)f2bf(tile[tx][ty + r]);
  } else {
    int i = (bx - 3936)*256 + tid;
    int s = i >> 5, p = i & 31;
    float inv = powf(10000.f, -2.f*(float)p/64.f);
    float a = (float)s * inv;
    tab[i] = make_float2(cosf(a), sinf(a));
  }
}

// --- GEMM1: 128x128, BK=32, 3-buffer LDS pipeline, vmcnt NEVER 0 mid-loop ---
__global__ __launch_bounds__(256, 3) void gemm1_rope(
    const short* __restrict__ Abf, const short* __restrict__ Wt,
    const float* __restrict__ bias, const float2* __restrict__ tab,
    short* __restrict__ Qr, short* __restrict__ Kr)
{
  __shared__ short As[3][4096];       // 3 x 8 KB (128 rows x 32 k)
  __shared__ short Bs[3][4096];       // 3 x 8 KB
  const int tid  = threadIdx.x;
  const int lane = tid & 63, w = tid >> 6;
  const int lr = lane & 15, h = lane >> 4;
  const int lk = h * 8;
  const int wm = (w >> 1) * 64, wn = (w & 1) * 64;
  const int m0 = blockIdx.x * 128;    // 64 m-tiles
  const int n0 = blockIdx.y * 128;    // 9 n-tiles (= entity type)

  const short* aS = Abf + (size_t)(m0 + (tid >> 2)) * H_ + (tid & 3) * 8;
  const short* bS = Wt  + (size_t)(n0 + (tid >> 2)) * H_ + (tid & 3) * 8;
  const int dOff = tid * 8;           // shorts; rows 64..127 at +2048 shorts

#define STAGE(buf, k0) do{ \
    __builtin_amdgcn_global_load_lds(GLB(aS + (k0)),         LDSP(&As[buf][dOff]),        16, 0, 0); \
    __builtin_amdgcn_global_load_lds(GLB(aS + 64*H_ + (k0)), LDSP(&As[buf][dOff + 2048]), 16, 0, 0); \
    __builtin_amdgcn_global_load_lds(GLB(bS + (k0)),         LDSP(&Bs[buf][dOff]),        16, 0, 0); \
    __builtin_amdgcn_global_load_lds(GLB(bS + 64*H_ + (k0)), LDSP(&Bs[buf][dOff + 2048]), 16, 0, 0); \
  }while(0)

  f32x4 acc[4][4] = {};

  // prologue: stage tiles 0,1 (depth builds to 3 inside the loop)
  STAGE(0, 0);
  STAGE(1, 32);
  asm volatile("s_waitcnt vmcnt(4)\n\ts_barrier" ::: "memory");  // tile0 landed, tile1 flying

  int cur = 0;
  for(int it = 0; it < NT1; ++it){
    if(it + 2 < NT1){
      const int nb = (cur + 2 >= 3) ? cur - 1 : cur + 2;
      STAGE(nb, (it + 2) * 32);       // overwrites buffer read in it-1 (all waves past barrier)
    }

    bf16x8 aF[4], bF[4];
    #pragma unroll
    for(int i = 0; i < 4; ++i) aF[i] = *(const bf16x8*)(&As[cur][(wm + i*16 + lr)*32 + lk]);
    #pragma unroll
    for(int j = 0; j < 4; ++j) bF[j] = *(const bf16x8*)(&Bs[cur][(wn + j*16 + lr)*32 + lk]);
    #pragma unroll
    for(int i = 0; i < 4; ++i)
      #pragma unroll
      for(int j = 0; j < 4; ++j)
        acc[i][j] = __builtin_amdgcn_mfma_f32_16x16x32_bf16(bF[j], aF[i], acc[i][j], 0, 0, 0);

    // end-of-iter: ensure stage(it+1) landed for ALL waves; keep stage(it+2) in flight
    if(it + 2 < NT1)       asm volatile("s_waitcnt vmcnt(4)\n\ts_barrier" ::: "memory");
    else if(it + 1 < NT1)  asm volatile("s_waitcnt vmcnt(0)\n\ts_barrier" ::: "memory");
    cur = (cur + 1 >= 3) ? 0 : cur + 1;
  }

  // epilogue: bias + lane-local RoPE + packed 4B stores (regs = 4 consecutive n)
  const int t = blockIdx.y;
  #pragma unroll
  for(int i = 0; i < 4; ++i){
    int m  = m0 + wm + i*16 + lr;
    int bi = m >> 9, sp = m & 511;
    size_t rowoff = ((size_t)(bi*T_ + t)*S_ + sp)*HD_;
    #pragma unroll
    for(int j = 0; j < 4; ++j){
      int nq  = n0 + wn + j*16 + (h << 2);
      int hd0 = (nq >> 1) & 63;
      int p   = (nq >> 2) & 31;
      float4 bv = *(const float4*)(bias + nq);
      float2 cs = tab[sp*32 + p];
      float q0 = acc[i][j][0] + bv.x;
      float k0v= acc[i][j][1] + bv.y;
      float q1 = acc[i][j][2] + bv.z;
      float k1v= acc[i][j][3] + bv.w;
      float rq0 = q0*cs.x - q1*cs.y, rq1 = q1*cs.x + q0*cs.y;
      float rk0 = k0v*cs.x - k1v*cs.y, rk1 = k1v*cs.x + k0v*cs.y;
      unsigned uq = (unsigned)f2bf(rq0) | ((unsigned)f2bf(rq1) << 16);
      unsigned uk = (unsigned)f2bf(rk0) | ((unsigned)f2bf(rk1) << 16);
      *(unsigned*)(Qr + rowoff + hd0) = uq;
      *(unsigned*)(Kr + rowoff + hd0) = uk;
    }
  }
#undef STAGE
}

// --- biaffine, XCD-swizzled, triangle-classified, nontemporal stores ---
__global__ __launch_bounds__(256) void gemm2_mask(
    const short* __restrict__ Qr, const short* __restrict__ Kr,
    const int* __restrict__ am, float* __restrict__ out)
{
  const int lane = threadIdx.x & 63;
  const int w    = threadIdx.x >> 6;
  const int wg   = ((blockIdx.x & 7) * 288) + (blockIdx.x >> 3);
  const int bt   = wg >> 4;
  const int tile = wg & 15;
  const int mt   = tile >> 2, nt = tile & 3;
  const int b    = bt / T_;
  const int n0   = nt * 128 + (w & 1) * 64;
  const int m0   = mt * 128 + (w >> 1) * 64;
  const int lr   = lane & 15;
  const int lk   = (lane >> 4) * 8;
  const int* amb = am + b * S_;

  if(mt > nt){                         // strictly lower: constant under fp32 rounding
    #pragma unroll
    for(int i = 0; i < 4; ++i){
      int m = m0 + i*16 + lr;
      float amm = (float)amb[m];
      float* orow = out + ((size_t)bt*S_ + m)*S_;
      #pragma unroll
      for(int j = 0; j < 4; ++j){
        int nq = n0 + j*16 + ((lane >> 4) << 2);
        int4 a4 = *(const int4*)(amb + nq);
        nt_store4(orow + nq,
                  -(1.f - amm*(float)a4.x)*1e12f - 1e12f,
                  -(1.f - amm*(float)a4.y)*1e12f - 1e12f,
                  -(1.f - amm*(float)a4.z)*1e12f - 1e12f,
                  -(1.f - amm*(float)a4.w)*1e12f - 1e12f);
      }
    }
    return;
  }

  const short* Q = Qr + (size_t)bt * S_ * HD_;
  const short* K = Kr + (size_t)bt * S_ * HD_;
  f32x4 acc[4][4] = {};

  #pragma unroll
  for(int ks = 0; ks < HD_; ks += 32){
    bf16x8 aF[4], bF[4];
    #pragma unroll
    for(int i = 0; i < 4; ++i) aF[i] = *(const bf16x8*)(Q + (size_t)(m0 + i*16 + lr)*HD_ + ks + lk);
    #pragma unroll
    for(int j = 0; j < 4; ++j) bF[j] = *(const bf16x8*)(K + (size_t)(n0 + j*16 + lr)*HD_ + ks + lk);
    #pragma unroll
    for(int i = 0; i < 4; ++i)
      #pragma unroll
      for(int j = 0; j < 4; ++j)
        acc[i][j] = __builtin_amdgcn_mfma_f32_16x16x32_bf16(bF[j], aF[i], acc[i][j], 0, 0, 0);
  }

  const bool diag = (mt == nt);
  #pragma unroll
  for(int i = 0; i < 4; ++i){
    int m = m0 + i*16 + lr;
    float amm = (float)amb[m];
    float* orow = out + ((size_t)bt*S_ + m)*S_;
    #pragma unroll
    for(int j = 0; j < 4; ++j){
      int nq = n0 + j*16 + ((lane >> 4) << 2);
      int4 a4 = *(const int4*)(amb + nq);
      float rx = acc[i][j][0]*0.125f - (1.f - amm*(float)a4.x)*1e12f;
      float ry = acc[i][j][1]*0.125f - (1.f - amm*(float)a4.y)*1e12f;
      float rz = acc[i][j][2]*0.125f - (1.f - amm*(float)a4.z)*1e12f;
      float rw = acc[i][j][3]*0.125f - (1.f - amm*(float)a4.w)*1e12f;
      if(diag){
        if((nq+0) < m) rx -= 1e12f;
        if((nq+1) < m) ry -= 1e12f;
        if((nq+2) < m) rz -= 1e12f;
        if((nq+3) < m) rw -= 1e12f;
      }
      nt_store4(orow + nq, rx, ry, rz, rw);
    }
  }
}

extern "C" void kernel_launch(void* const* d_in, const int* in_sizes, int n_in,
                              void* d_out, int out_size, void* d_ws, size_t ws_size,
                              hipStream_t stream)
{
  const float* hs    = (const float*)d_in[0];
  const int*   amask = (const int*)  d_in[1];
  const float* W     = (const float*)d_in[2];
  const float* bias  = (const float*)d_in[3];
  float* out = (float*)d_out;

  char* ws = (char*)d_ws;
  short*  Wt  = (short*) (ws);                       // 1,769,472 B
  float2* tab = (float2*)(ws + 1769472);             //   131,072 B
  short*  Qr  = (short*) (ws + 1900544);             // 9,437,184 B
  short*  Kr  = (short*) (ws + 11337728);            // 9,437,184 B
  short*  Abf = (short*) (ws + 20774912);            // 12,582,912 B

  prep_all  <<<4000, 256, 0, stream>>>(hs, Abf, W, Wt, tab);
  gemm1_rope<<<dim3(M1/128, N1/128), 256, 0, stream>>>(Abf, Wt, bias, tab, Qr, Kr);
  gemm2_mask<<<2304, 256, 0, stream>>>(Qr, Kr, amask, out);
}

// Round 17
// 82.591 us; speedup vs baseline: 1.1640x; 1.1404x over previous
//
#include <hip/hip_runtime.h>

#define B_  16
#define S_  512
#define H_  768
#define T_  9
#define HD_ 64
#define N1  (T_*HD_*2)   // 1152
#define M1  (B_*S_)      // 8192
#define NT1 (H_/32)      // 24 K-tiles

typedef __attribute__((ext_vector_type(8))) short bf16x8;
typedef __attribute__((ext_vector_type(4))) float f32x4;

#define GLB(p) ((const __attribute__((address_space(1))) void*)(p))
#define LDSP(p) ((__attribute__((address_space(3))) void*)(p))

__device__ inline unsigned short f2bf(float f){
  union { float f; unsigned u; } v; v.f = f;
  unsigned r = v.u + 0x7fffu + ((v.u >> 16) & 1u);   // RNE
  return (unsigned short)(r >> 16);
}

// --- merged prep: hs->bf16 | W transpose->bf16 | trig table ---
__global__ __launch_bounds__(256) void prep_all(
    const float* __restrict__ hs, short* __restrict__ Abf,
    const float* __restrict__ W, short* __restrict__ Wt,
    float2* __restrict__ tab)
{
  __shared__ float tile[32][33];
  const int bx = blockIdx.x, tid = threadIdx.x;
  if(bx < 3072){
    int i = bx*2048 + tid*8;
    float4 a0 = *(const float4*)(hs + i);
    float4 a1 = *(const float4*)(hs + i + 4);
    bf16x8 r;
    r[0]=f2bf(a0.x); r[1]=f2bf(a0.y); r[2]=f2bf(a0.z); r[3]=f2bf(a0.w);
    r[4]=f2bf(a1.x); r[5]=f2bf(a1.y); r[6]=f2bf(a1.z); r[7]=f2bf(a1.w);
    *(bf16x8*)(Abf + i) = r;
  } else if(bx < 3936){
    int idx = bx - 3072;
    int n0 = (idx % 36)*32, k0 = (idx / 36)*32;
    int tx = tid & 31, ty = tid >> 5;
    #pragma unroll
    for(int r = 0; r < 32; r += 8)
      tile[ty + r][tx] = W[(size_t)(k0 + ty + r)*N1 + n0 + tx];
    __syncthreads();
    #pragma unroll
    for(int r = 0; r < 32; r += 8)
      Wt[(size_t)(n0 + ty + r)*H_ + k0 + tx] = (short)f2bf(tile[tx][ty + r]);
  } else {
    int i = (bx - 3936)*256 + tid;
    int s = i >> 5, p = i & 31;
    float inv = powf(10000.f, -2.f*(float)p/64.f);
    float a = (float)s * inv;
    tab[i] = make_float2(cosf(a), sinf(a));
  }
}

// --- GEMM1: 128x128, BK=32, 3-buffer LDS pipeline, vmcnt NEVER 0 mid-loop ---
__global__ __launch_bounds__(256, 3) void gemm1_rope(
    const short* __restrict__ Abf, const short* __restrict__ Wt,
    const float* __restrict__ bias, const float2* __restrict__ tab,
    short* __restrict__ Qr, short* __restrict__ Kr)
{
  __shared__ short As[3][4096];       // 3 x 8 KB (128 rows x 32 k)
  __shared__ short Bs[3][4096];       // 3 x 8 KB
  const int tid  = threadIdx.x;
  const int lane = tid & 63, w = tid >> 6;
  const int lr = lane & 15, h = lane >> 4;
  const int lk = h * 8;
  const int wm = (w >> 1) * 64, wn = (w & 1) * 64;
  const int m0 = blockIdx.x * 128;    // 64 m-tiles
  const int n0 = blockIdx.y * 128;    // 9 n-tiles (= entity type)

  const short* aS = Abf + (size_t)(m0 + (tid >> 2)) * H_ + (tid & 3) * 8;
  const short* bS = Wt  + (size_t)(n0 + (tid >> 2)) * H_ + (tid & 3) * 8;
  const int dOff = tid * 8;           // shorts; rows 64..127 at +2048 shorts

#define STAGE(buf, k0) do{ \
    __builtin_amdgcn_global_load_lds(GLB(aS + (k0)),         LDSP(&As[buf][dOff]),        16, 0, 0); \
    __builtin_amdgcn_global_load_lds(GLB(aS + 64*H_ + (k0)), LDSP(&As[buf][dOff + 2048]), 16, 0, 0); \
    __builtin_amdgcn_global_load_lds(GLB(bS + (k0)),         LDSP(&Bs[buf][dOff]),        16, 0, 0); \
    __builtin_amdgcn_global_load_lds(GLB(bS + 64*H_ + (k0)), LDSP(&Bs[buf][dOff + 2048]), 16, 0, 0); \
  }while(0)

  f32x4 acc[4][4] = {};

  // prologue: stage tiles 0,1 (depth builds to 3 inside the loop)
  STAGE(0, 0);
  STAGE(1, 32);
  asm volatile("s_waitcnt vmcnt(4)\n\ts_barrier" ::: "memory");  // tile0 landed, tile1 flying

  int cur = 0;
  for(int it = 0; it < NT1; ++it){
    if(it + 2 < NT1){
      const int nb = (cur + 2 >= 3) ? cur - 1 : cur + 2;
      STAGE(nb, (it + 2) * 32);       // overwrites buffer read in it-1 (all waves past barrier)
    }

    bf16x8 aF[4], bF[4];
    #pragma unroll
    for(int i = 0; i < 4; ++i) aF[i] = *(const bf16x8*)(&As[cur][(wm + i*16 + lr)*32 + lk]);
    #pragma unroll
    for(int j = 0; j < 4; ++j) bF[j] = *(const bf16x8*)(&Bs[cur][(wn + j*16 + lr)*32 + lk]);
    #pragma unroll
    for(int i = 0; i < 4; ++i)
      #pragma unroll
      for(int j = 0; j < 4; ++j)
        acc[i][j] = __builtin_amdgcn_mfma_f32_16x16x32_bf16(bF[j], aF[i], acc[i][j], 0, 0, 0);

    // end-of-iter: ensure stage(it+1) landed for ALL waves; keep stage(it+2) in flight
    if(it + 2 < NT1)       asm volatile("s_waitcnt vmcnt(4)\n\ts_barrier" ::: "memory");
    else if(it + 1 < NT1)  asm volatile("s_waitcnt vmcnt(0)\n\ts_barrier" ::: "memory");
    cur = (cur + 1 >= 3) ? 0 : cur + 1;
  }

  // epilogue: bias + lane-local RoPE + packed 4B stores (regs = 4 consecutive n)
  const int t = blockIdx.y;
  #pragma unroll
  for(int i = 0; i < 4; ++i){
    int m  = m0 + wm + i*16 + lr;
    int bi = m >> 9, sp = m & 511;
    size_t rowoff = ((size_t)(bi*T_ + t)*S_ + sp)*HD_;
    #pragma unroll
    for(int j = 0; j < 4; ++j){
      int nq  = n0 + wn + j*16 + (h << 2);
      int hd0 = (nq >> 1) & 63;
      int p   = (nq >> 2) & 31;
      float4 bv = *(const float4*)(bias + nq);
      float2 cs = tab[sp*32 + p];
      float q0 = acc[i][j][0] + bv.x;
      float k0v= acc[i][j][1] + bv.y;
      float q1 = acc[i][j][2] + bv.z;
      float k1v= acc[i][j][3] + bv.w;
      float rq0 = q0*cs.x - q1*cs.y, rq1 = q1*cs.x + q0*cs.y;
      float rk0 = k0v*cs.x - k1v*cs.y, rk1 = k1v*cs.x + k0v*cs.y;
      unsigned uq = (unsigned)f2bf(rq0) | ((unsigned)f2bf(rq1) << 16);
      unsigned uk = (unsigned)f2bf(rk0) | ((unsigned)f2bf(rk1) << 16);
      *(unsigned*)(Qr + rowoff + hd0) = uq;
      *(unsigned*)(Kr + rowoff + hd0) = uk;
    }
  }
#undef STAGE
}

// --- biaffine, XCD-swizzled, triangle-classified tiles ---
__global__ __launch_bounds__(256) void gemm2_mask(
    const short* __restrict__ Qr, const short* __restrict__ Kr,
    const int* __restrict__ am, float* __restrict__ out)
{
  const int lane = threadIdx.x & 63;
  const int w    = threadIdx.x >> 6;
  const int wg   = ((blockIdx.x & 7) * 288) + (blockIdx.x >> 3);
  const int bt   = wg >> 4;
  const int tile = wg & 15;
  const int mt   = tile >> 2, nt = tile & 3;
  const int b    = bt / T_;
  const int n0   = nt * 128 + (w & 1) * 64;
  const int m0   = mt * 128 + (w >> 1) * 64;
  const int lr   = lane & 15;
  const int lk   = (lane >> 4) * 8;
  const int* amb = am + b * S_;

  if(mt > nt){                         // strictly lower: constant under fp32 rounding
    #pragma unroll
    for(int i = 0; i < 4; ++i){
      int m = m0 + i*16 + lr;
      float amm = (float)amb[m];
      float* orow = out + ((size_t)bt*S_ + m)*S_;
      #pragma unroll
      for(int j = 0; j < 4; ++j){
        int nq = n0 + j*16 + ((lane >> 4) << 2);
        int4 a4 = *(const int4*)(amb + nq);
        float4 r;
        r.x = -(1.f - amm*(float)a4.x)*1e12f - 1e12f;
        r.y = -(1.f - amm*(float)a4.y)*1e12f - 1e12f;
        r.z = -(1.f - amm*(float)a4.z)*1e12f - 1e12f;
        r.w = -(1.f - amm*(float)a4.w)*1e12f - 1e12f;
        *(float4*)(orow + nq) = r;
      }
    }
    return;
  }

  const short* Q = Qr + (size_t)bt * S_ * HD_;
  const short* K = Kr + (size_t)bt * S_ * HD_;
  f32x4 acc[4][4] = {};

  #pragma unroll
  for(int ks = 0; ks < HD_; ks += 32){
    bf16x8 aF[4], bF[4];
    #pragma unroll
    for(int i = 0; i < 4; ++i) aF[i] = *(const bf16x8*)(Q + (size_t)(m0 + i*16 + lr)*HD_ + ks + lk);
    #pragma unroll
    for(int j = 0; j < 4; ++j) bF[j] = *(const bf16x8*)(K + (size_t)(n0 + j*16 + lr)*HD_ + ks + lk);
    #pragma unroll
    for(int i = 0; i < 4; ++i)
      #pragma unroll
      for(int j = 0; j < 4; ++j)
        acc[i][j] = __builtin_amdgcn_mfma_f32_16x16x32_bf16(bF[j], aF[i], acc[i][j], 0, 0, 0);
  }

  const bool diag = (mt == nt);
  #pragma unroll
  for(int i = 0; i < 4; ++i){
    int m = m0 + i*16 + lr;
    float amm = (float)amb[m];
    float* orow = out + ((size_t)bt*S_ + m)*S_;
    #pragma unroll
    for(int j = 0; j < 4; ++j){
      int nq = n0 + j*16 + ((lane >> 4) << 2);
      int4 a4 = *(const int4*)(amb + nq);
      float4 r;
      r.x = acc[i][j][0]*0.125f - (1.f - amm*(float)a4.x)*1e12f;
      r.y = acc[i][j][1]*0.125f - (1.f - amm*(float)a4.y)*1e12f;
      r.z = acc[i][j][2]*0.125f - (1.f - amm*(float)a4.z)*1e12f;
      r.w = acc[i][j][3]*0.125f - (1.f - amm*(float)a4.w)*1e12f;
      if(diag){                        // only diagonal tiles need the triu compare
        if((nq+0) < m) r.x -= 1e12f;
        if((nq+1) < m) r.y -= 1e12f;
        if((nq+2) < m) r.z -= 1e12f;
        if((nq+3) < m) r.w -= 1e12f;
      }
      *(float4*)(orow + nq) = r;
    }
  }
}

extern "C" void kernel_launch(void* const* d_in, const int* in_sizes, int n_in,
                              void* d_out, int out_size, void* d_ws, size_t ws_size,
                              hipStream_t stream)
{
  const float* hs    = (const float*)d_in[0];
  const int*   amask = (const int*)  d_in[1];
  const float* W     = (const float*)d_in[2];
  const float* bias  = (const float*)d_in[3];
  float* out = (float*)d_out;

  char* ws = (char*)d_ws;
  short*  Wt  = (short*) (ws);                       // 1,769,472 B
  float2* tab = (float2*)(ws + 1769472);             //   131,072 B
  short*  Qr  = (short*) (ws + 1900544);             // 9,437,184 B
  short*  Kr  = (short*) (ws + 11337728);            // 9,437,184 B
  short*  Abf = (short*) (ws + 20774912);            // 12,582,912 B

  prep_all  <<<4000, 256, 0, stream>>>(hs, Abf, W, Wt, tab);
  gemm1_rope<<<dim3(M1/128, N1/128), 256, 0, stream>>>(Abf, Wt, bias, tab, Qr, Kr);
  gemm2_mask<<<2304, 256, 0, stream>>>(Qr, Kr, amask, out);
}